// Round 6
// baseline (5493.288 us; speedup 1.0000x reference)
//
#include <hip/hip_runtime.h>
#include <hip/hip_bf16.h>
#include <type_traits>

// HGConv layer: micro (per-relation GAT) + macro (semantic attention) + gated residual.
// I/O dtype: FLOAT32 (per reference; rounds 0-5 wrongly assumed bf16 -> garbage
// exponents from reading f32 as bf16 -> NaN / 3.6e37). Internals: bf16 node
// matrices, f32 accumulation. Workspace: exactly 51,200,000 B (proven available
// by round-5 tier branch).

#define N_AUTHOR 50000
#define N_PAPER  50000
#define NEDGE    400000
#define KDIM     256
#define NHEAD    8
#define SLOPE    0.2f

using bf16 = __hip_bfloat16;

__device__ __forceinline__ float us2f(unsigned short u) {
    return __uint_as_float(((unsigned int)u) << 16);
}
__device__ __forceinline__ float fin(float v) {   // 0 if NaN/Inf
    return (((__float_as_uint(v) >> 23) & 0xFF) != 0xFF) ? v : 0.f;
}
__device__ __forceinline__ unsigned short f2bu(float f) {
    f = fin(f);
    bf16 h = __float2bfloat16(f);
    return *reinterpret_cast<unsigned short*>(&h);
}
__device__ __forceinline__ int clampi(int v, int hi) {
    return v < 0 ? 0 : (v >= hi ? hi - 1 : v);
}

// ---------------------------------------------------------------------------
// Diagnostic marker (f32 output)
// ---------------------------------------------------------------------------
__global__ void fill_marker(float* __restrict__ out, int total, float c)
{
    int i = blockIdx.x * blockDim.x + threadIdx.x;
    if (i < total) out[i] = c;
}

// ---------------------------------------------------------------------------
// GEMM: C[M x 256] = A[M x 256] @ W[256 x 256](f32), f32 accumulate.
// TA: float or bf16 (A matrix). TC: bf16 (internal) or float (final).
// MODE 0: C = (TC)acc
// MODE 2: C = sig(g)*other(bf16) + (1-sig(g))*(acc + bias)   [final, TC=float]
// Tile 64x64, BK=32, 256 threads, 4x4/thread. No aliasing; C never read.
// ---------------------------------------------------------------------------
template<int MODE, typename TA, typename TC>
__global__ __launch_bounds__(256) void gemm64(
    const TA* __restrict__ A, const float* __restrict__ W, int M,
    TC* __restrict__ C,
    const float* __restrict__ bias, const bf16* __restrict__ other,
    const float* __restrict__ gate)
{
    __shared__ float As[32][68];
    __shared__ float Bs[32][68];
    const int tid = threadIdx.x;
    const int tx = tid & 15, ty = tid >> 4;
    const int rowBase = blockIdx.y * 64;
    const int colBase = blockIdx.x * 64;
    float acc[4][4] = {};

    for (int kt = 0; kt < 256; kt += 32) {
        {   // A tile: 64 rows x 32 k -> As[k][row]
            int r = tid >> 3;
            int kq = (tid & 7) << 2;
            #pragma unroll
            for (int h = 0; h < 2; ++h, r += 32) {
                int grow = rowBase + r;
                float f0 = 0.f, f1 = 0.f, f2 = 0.f, f3 = 0.f;
                if (grow < M) {
                    if constexpr (std::is_same<TA, float>::value) {
                        float4 v = *reinterpret_cast<const float4*>(
                            A + (size_t)grow * KDIM + kt + kq);
                        f0 = v.x; f1 = v.y; f2 = v.z; f3 = v.w;
                    } else {
                        ushort4 v = *reinterpret_cast<const ushort4*>(
                            reinterpret_cast<const unsigned short*>(A)
                            + (size_t)grow * KDIM + kt + kq);
                        f0 = us2f(v.x); f1 = us2f(v.y); f2 = us2f(v.z); f3 = us2f(v.w);
                    }
                }
                As[kq + 0][r] = f0; As[kq + 1][r] = f1;
                As[kq + 2][r] = f2; As[kq + 3][r] = f3;
            }
        }
        {   // B tile (W is f32): 32 k x 64 cols
            int kk = tid >> 4;
            int cq = (tid & 15) << 2;
            #pragma unroll
            for (int h = 0; h < 2; ++h, kk += 16) {
                float4 v = *reinterpret_cast<const float4*>(
                    W + (size_t)(kt + kk) * KDIM + colBase + cq);
                *reinterpret_cast<float4*>(&Bs[kk][cq]) = v;
            }
        }
        __syncthreads();
        #pragma unroll 8
        for (int kk = 0; kk < 32; ++kk) {
            float4 a4 = *reinterpret_cast<const float4*>(&As[kk][ty << 2]);
            float4 b4 = *reinterpret_cast<const float4*>(&Bs[kk][tx << 2]);
            float av[4] = {a4.x, a4.y, a4.z, a4.w};
            float bv[4] = {b4.x, b4.y, b4.z, b4.w};
            #pragma unroll
            for (int i = 0; i < 4; ++i)
                #pragma unroll
                for (int j = 0; j < 4; ++j)
                    acc[i][j] = fmaf(av[i], bv[j], acc[i][j]);
        }
        __syncthreads();
    }

    float al = 0.f;
    if (MODE == 2) al = 1.f / (1.f + expf(-gate[0]));

    #pragma unroll
    for (int i = 0; i < 4; ++i) {
        int row = rowBase + (ty << 2) + i;
        if (row < M) {
            int col0 = colBase + (tx << 2);
            size_t base = (size_t)row * KDIM + col0;
            float v[4];
            #pragma unroll
            for (int j = 0; j < 4; ++j) v[j] = acc[i][j];
            if (MODE == 2) {
                ushort4 ov = *reinterpret_cast<const ushort4*>(
                    reinterpret_cast<const unsigned short*>(other) + base);
                float of[4] = {us2f(ov.x), us2f(ov.y), us2f(ov.z), us2f(ov.w)};
                #pragma unroll
                for (int j = 0; j < 4; ++j)
                    v[j] = al * fin(of[j]) + (1.f - al) * (v[j] + bias[col0 + j]);
            }
            if constexpr (std::is_same<TC, float>::value) {
                float4 o;
                o.x = fin(v[0]); o.y = fin(v[1]); o.z = fin(v[2]); o.w = fin(v[3]);
                *reinterpret_cast<float4*>(C + base) = o;
            } else {
                ushort4 o;
                o.x = f2bu(v[0]); o.y = f2bu(v[1]); o.z = f2bu(v[2]); o.w = f2bu(v[3]);
                *reinterpret_cast<ushort4*>(
                    reinterpret_cast<unsigned short*>(C) + base) = o;
            }
        }
    }
}

// ---------------------------------------------------------------------------
// Per-node per-head attention dot: out[n*8+k] = sum_d proj[n,k*32+d]*attn[k*64+off+d]
// proj: bf16 internal; attn: f32 input.
// ---------------------------------------------------------------------------
__global__ void head_dot(const bf16* __restrict__ proj, const float* __restrict__ attn,
                         int off, int N, float* __restrict__ out)
{
    int gid = blockIdx.x * blockDim.x + threadIdx.x;
    if (gid >= N * NHEAD) return;
    int n = gid >> 3, k = gid & 7;
    const unsigned short* p =
        reinterpret_cast<const unsigned short*>(proj) + (size_t)n * KDIM + k * 32;
    const float* a = attn + k * 64 + off;
    float s = 0.f;
    #pragma unroll
    for (int d0 = 0; d0 < 32; d0 += 4) {
        ushort4 pv = *reinterpret_cast<const ushort4*>(p + d0);
        float4 av = *reinterpret_cast<const float4*>(a + d0);
        s += us2f(pv.x) * av.x + us2f(pv.y) * av.y
           + us2f(pv.z) * av.z + us2f(pv.w) * av.w;
    }
    out[gid] = fin(s);
}

// ---------------------------------------------------------------------------
// Edge pass A: ssum[dst,k] += exp(leakyrelu(el[src]+er[dst])), arg clamped at 30.
// (No max-subtraction: logits O(1); softmax shift-invariant.)
// ---------------------------------------------------------------------------
__global__ void edge_logits(const int* __restrict__ src, const int* __restrict__ dst,
                            const float* __restrict__ el, const float* __restrict__ er,
                            float* __restrict__ ssum, int E)
{
    int gid = blockIdx.x * blockDim.x + threadIdx.x;
    if (gid >= E * NHEAD) return;
    int e = gid >> 3, k = gid & 7;
    int s = clampi(src[e], N_PAPER), d = clampi(dst[e], N_PAPER);
    float v = el[s * NHEAD + k] + er[d * NHEAD + k];
    v = v > 0.f ? v : SLOPE * v;
    atomicAdd(&ssum[d * NHEAD + k], fin(expf(fminf(v, 30.f))));
}

// ---------------------------------------------------------------------------
// Edge pass B (column-chunked): ftc[dst, 64-col chunk] += feat[src, chunk] * a.
// 16 edges/block x 16 lanes; lane covers 4 cols.
// ---------------------------------------------------------------------------
__global__ __launch_bounds__(256) void edge_aggregate_chunk(
    const int* __restrict__ src, const int* __restrict__ dst,
    const float* __restrict__ el, const float* __restrict__ er,
    const float* __restrict__ ssum, const bf16* __restrict__ feat,
    float* __restrict__ ftc, int E, int cb)
{
    int t = threadIdx.x;
    int e = blockIdx.x * 16 + (t >> 4);
    if (e >= E) return;
    int l = t & 15;
    int col = cb + l * 4;
    int head = col >> 5;
    int s = clampi(src[e], N_PAPER), d = clampi(dst[e], N_PAPER);
    float v = el[s * NHEAD + head] + er[d * NHEAD + head];
    v = v > 0.f ? v : SLOPE * v;
    float a = expf(fminf(v, 30.f)) / fmaxf(ssum[d * NHEAD + head], 1e-20f);
    a = fin(a);
    ushort4 fv = *reinterpret_cast<const ushort4*>(
        reinterpret_cast<const unsigned short*>(feat) + (size_t)s * KDIM + col);
    float* o = ftc + (size_t)d * 64 + l * 4;
    atomicAdd(o + 0, fin(us2f(fv.x) * a));
    atomicAdd(o + 1, fin(us2f(fv.y) * a));
    atomicAdd(o + 2, fin(us2f(fv.z) * a));
    atomicAdd(o + 3, fin(us2f(fv.w) * a));
}

// ---------------------------------------------------------------------------
// relu + cast of one 64-col chunk -> bf16 internal
// ---------------------------------------------------------------------------
__global__ void relu_cast_chunk(const float* __restrict__ ftc, bf16* __restrict__ out,
                                int N, int cb)
{
    int gid = blockIdx.x * blockDim.x + threadIdx.x;
    if (gid >= N * 16) return;
    int n = gid >> 4, jj = (gid & 15) * 4;
    float4 v = *reinterpret_cast<const float4*>(ftc + (size_t)n * 64 + jj);
    ushort4 o;
    o.x = f2bu(fmaxf(v.x, 0.f)); o.y = f2bu(fmaxf(v.y, 0.f));
    o.z = f2bu(fmaxf(v.z, 0.f)); o.w = f2bu(fmaxf(v.w, 0.f));
    *reinterpret_cast<ushort4*>(
        reinterpret_cast<unsigned short*>(out) + (size_t)n * KDIM + cb + jj) = o;
}

// ---------------------------------------------------------------------------
// Fused paper macro: for head h (blockIdx.y), rows [rb, rb+64):
//   rfw = r_writes @ W_rel_w[:,h], rfc = r_cites @ W_rel_c[:,h],
//   node = feats_p(f32) @ W_node_p[:,h]; semantic attention over {writes,cites}
// -> out(bf16)[rows, h*32..h*32+32).
// ---------------------------------------------------------------------------
__global__ __launch_bounds__(256) void rf_fuse_head(
    const bf16* __restrict__ rW, const bf16* __restrict__ rC,
    const float* __restrict__ fP,
    const float* __restrict__ Ww, const float* __restrict__ Wc,
    const float* __restrict__ Wn, const float* __restrict__ attn,
    bf16* __restrict__ out, int M)
{
    __shared__ float AsW[64][33], AsC[64][33], AsN[64][33];
    __shared__ float WsW[32][32], WsC[32][32], WsN[32][32];
    const int t = threadIdx.x;
    const int r2 = t >> 2, cg = t & 3;
    const int h = blockIdx.y;
    const int rb = blockIdx.x * 64;
    const int lkq = cg * 8;
    const int wk = t >> 3, wcq = (t & 7) * 4;
    const unsigned short* rWu = reinterpret_cast<const unsigned short*>(rW);
    const unsigned short* rCu = reinterpret_cast<const unsigned short*>(rC);
    const bool rok = (rb + r2) < M;

    float accW[8] = {}, accC[8] = {}, accN[8] = {};

    for (int kt = 0; kt < 256; kt += 32) {
        {
            size_t ab = (size_t)(rb + r2) * KDIM + kt + lkq;
            ushort4 w0 = {0,0,0,0}, w1 = w0, c0 = w0, c1 = w0;
            float4 n0 = {0.f,0.f,0.f,0.f}, n1 = n0;
            if (rok) {
                w0 = *reinterpret_cast<const ushort4*>(rWu + ab);
                w1 = *reinterpret_cast<const ushort4*>(rWu + ab + 4);
                c0 = *reinterpret_cast<const ushort4*>(rCu + ab);
                c1 = *reinterpret_cast<const ushort4*>(rCu + ab + 4);
                n0 = *reinterpret_cast<const float4*>(fP + ab);
                n1 = *reinterpret_cast<const float4*>(fP + ab + 4);
            }
            AsW[r2][lkq+0]=us2f(w0.x); AsW[r2][lkq+1]=us2f(w0.y);
            AsW[r2][lkq+2]=us2f(w0.z); AsW[r2][lkq+3]=us2f(w0.w);
            AsW[r2][lkq+4]=us2f(w1.x); AsW[r2][lkq+5]=us2f(w1.y);
            AsW[r2][lkq+6]=us2f(w1.z); AsW[r2][lkq+7]=us2f(w1.w);
            AsC[r2][lkq+0]=us2f(c0.x); AsC[r2][lkq+1]=us2f(c0.y);
            AsC[r2][lkq+2]=us2f(c0.z); AsC[r2][lkq+3]=us2f(c0.w);
            AsC[r2][lkq+4]=us2f(c1.x); AsC[r2][lkq+5]=us2f(c1.y);
            AsC[r2][lkq+6]=us2f(c1.z); AsC[r2][lkq+7]=us2f(c1.w);
            AsN[r2][lkq+0]=n0.x; AsN[r2][lkq+1]=n0.y;
            AsN[r2][lkq+2]=n0.z; AsN[r2][lkq+3]=n0.w;
            AsN[r2][lkq+4]=n1.x; AsN[r2][lkq+5]=n1.y;
            AsN[r2][lkq+6]=n1.z; AsN[r2][lkq+7]=n1.w;
        }
        {
            size_t wb = (size_t)(kt + wk) * KDIM + h * 32 + wcq;
            float4 a = *reinterpret_cast<const float4*>(Ww + wb);
            float4 b = *reinterpret_cast<const float4*>(Wc + wb);
            float4 c = *reinterpret_cast<const float4*>(Wn + wb);
            *reinterpret_cast<float4*>(&WsW[wk][wcq]) = a;
            *reinterpret_cast<float4*>(&WsC[wk][wcq]) = b;
            *reinterpret_cast<float4*>(&WsN[wk][wcq]) = c;
        }
        __syncthreads();
        #pragma unroll 4
        for (int kk = 0; kk < 32; ++kk) {
            float aw = AsW[r2][kk], ac = AsC[r2][kk], an = AsN[r2][kk];
            #pragma unroll
            for (int j = 0; j < 8; ++j) {
                accW[j] = fmaf(aw, WsW[kk][cg*8+j], accW[j]);
                accC[j] = fmaf(ac, WsC[kk][cg*8+j], accC[j]);
                accN[j] = fmaf(an, WsN[kk][cg*8+j], accN[j]);
            }
        }
        __syncthreads();
    }

    float pL = 0.f, pW = 0.f, pC = 0.f;
    #pragma unroll
    for (int j = 0; j < 8; ++j) {
        int c = cg * 8 + j;
        float aL = attn[h * 64 + c];
        float aR = attn[h * 64 + 32 + c];
        pL = fmaf(accN[j], aL, pL);
        pW = fmaf(accW[j], aR, pW);
        pC = fmaf(accC[j], aR, pC);
    }
    pL += __shfl_xor(pL, 1, 4); pL += __shfl_xor(pL, 2, 4);
    pW += __shfl_xor(pW, 1, 4); pW += __shfl_xor(pW, 2, 4);
    pC += __shfl_xor(pC, 1, 4); pC += __shfl_xor(pC, 2, 4);
    float sw = pL + pW; sw = sw > 0.f ? sw : SLOPE * sw;
    float sc = pL + pC; sc = sc > 0.f ? sc : SLOPE * sc;
    float m = fmaxf(sw, sc);
    float ew = expf(sw - m), ec = expf(sc - m);
    float inv = 1.f / (ew + ec);
    ew *= inv; ec *= inv;

    if (rok) {
        unsigned short* ob = reinterpret_cast<unsigned short*>(out)
                           + (size_t)(rb + r2) * KDIM + h * 32 + cg * 8;
        ushort4 o0, o1;
        o0.x = f2bu(ew*accW[0] + ec*accC[0]); o0.y = f2bu(ew*accW[1] + ec*accC[1]);
        o0.z = f2bu(ew*accW[2] + ec*accC[2]); o0.w = f2bu(ew*accW[3] + ec*accC[3]);
        o1.x = f2bu(ew*accW[4] + ec*accC[4]); o1.y = f2bu(ew*accW[5] + ec*accC[5]);
        o1.z = f2bu(ew*accW[6] + ec*accC[6]); o1.w = f2bu(ew*accW[7] + ec*accC[7]);
        *reinterpret_cast<ushort4*>(ob) = o0;
        *reinterpret_cast<ushort4*>(ob + 4) = o1;
    }
}

// ---------------------------------------------------------------------------
extern "C" void kernel_launch(void* const* d_in, const int* in_sizes, int n_in,
                              void* d_out, int out_size, void* d_ws, size_t ws_size,
                              hipStream_t stream)
{
    // ---- environment validation (host-side, constant across calls) ----
    static const int expected[24] = {
        12800000, 12800000, 65536, 65536, 512, 512, 65536, 65536,
        65536, 65536, 65536, 512, 65536, 256, 65536, 256, 1, 1,
        400000, 400000, 400000, 400000, 400000, 400000};
    float marker = 0.f;
    if (n_in != 24) marker = 500.f;
    else {
        for (int i = 0; i < 24; ++i)
            if (in_sizes[i] != expected[i]) { marker = 200.f + 8.f * i; break; }
    }
    if (marker == 0.f && out_size != 25600000) marker = 600.f + (float)(out_size / 1000000);
    if (marker == 0.f && ws_size < 51200000ull) marker = 1000.f + (float)(ws_size / 1000000ull);
    if (marker != 0.f) {
        fill_marker<<<(out_size + 255) / 256, 256, 0, stream>>>((float*)d_out, out_size, marker);
        return;
    }

    const float* feats_a  = (const float*)d_in[0];
    const float* feats_p  = (const float*)d_in[1];
    const float* W_mic_a  = (const float*)d_in[2];
    const float* W_mic_p  = (const float*)d_in[3];
    const float* attn_a   = (const float*)d_in[4];
    const float* attn_p   = (const float*)d_in[5];
    // d_in[6] = W_macro_node_author: unused (author macro is passthrough)
    const float* W_node_p = (const float*)d_in[7];
    const float* W_rel_w  = (const float*)d_in[8];
    const float* W_rel_wb = (const float*)d_in[9];
    const float* W_rel_c  = (const float*)d_in[10];
    const float* attn_mac = (const float*)d_in[11];
    const float* W_res_a  = (const float*)d_in[12];
    const float* b_res_a  = (const float*)d_in[13];
    const float* W_res_p  = (const float*)d_in[14];
    const float* b_res_p  = (const float*)d_in[15];
    const float* rw_a     = (const float*)d_in[16];
    const float* rw_p     = (const float*)d_in[17];
    const int* w_src  = (const int*)d_in[18];
    const int* w_dst  = (const int*)d_in[19];
    const int* wb_src = (const int*)d_in[20];
    const int* wb_dst = (const int*)d_in[21];
    const int* c_src  = (const int*)d_in[22];
    const int* c_dst  = (const int*)d_in[23];

    const int NB = N_PAPER * KDIM;             // 12.8M elems
    // d_out (f32, 102.4MB): author half [0,NB) , paper half [NB,2NB).
    float* Oa_f = (float*)d_out;
    float* Op_f = Oa_f + NB;
    // bf16 scratch aliases inside each half (first 25.6MB of each 51.2MB half):
    bf16* Oa_b = (bf16*)d_out;                 // P_a -> r_written_by
    bf16* Op_b = (bf16*)Op_f;                  // P_p -> r_cites
    // d_ws (51.2e6 B): [A_ws bf16 NB = 25.6MB][X region 25.6MB]
    bf16* A_ws = (bf16*)d_ws;                  // r_writes
    char* Xb   = (char*)d_ws + (size_t)NB * 2;
    float* el_w  = (float*)Xb;                 // 5 x 400,000 f32 (8MB)
    float* er_w  = el_w + 400000;
    float* el_p  = el_w + 800000;
    float* er_wb = el_w + 1200000;
    float* er_c  = el_w + 1600000;
    float* ssum  = el_w + 2000000;             // 1.6MB
    float* ftc   = el_w + 2400000;             // 12.8MB chunk scratch (ends 22.4MB)
    bf16*  X     = (bf16*)Xb;                  // later: rf_written_by -> fused_paper

    dim3 gblk(256);
    dim3 ggrid(KDIM / 64, (N_PAPER + 63) / 64);

    // 1-2: micro projections (f32 feats @ f32 W -> bf16 P in d_out halves)
    gemm64<0, float, bf16><<<ggrid, gblk, 0, stream>>>(feats_a, W_mic_a, N_AUTHOR, Oa_b, nullptr, nullptr, nullptr);
    gemm64<0, float, bf16><<<ggrid, gblk, 0, stream>>>(feats_p, W_mic_p, N_PAPER,  Op_b, nullptr, nullptr, nullptr);

    // 3: per-head attention dots (attn keyed by SRC node type per relation)
    int hdB = (N_PAPER * NHEAD + 255) / 256;
    head_dot<<<hdB, 256, 0, stream>>>(Oa_b, attn_a, 0,  N_AUTHOR, el_w);
    head_dot<<<hdB, 256, 0, stream>>>(Op_b, attn_a, 32, N_PAPER,  er_w);
    head_dot<<<hdB, 256, 0, stream>>>(Op_b, attn_p, 0,  N_PAPER,  el_p);
    head_dot<<<hdB, 256, 0, stream>>>(Oa_b, attn_p, 32, N_AUTHOR, er_wb);
    head_dot<<<hdB, 256, 0, stream>>>(Op_b, attn_p, 32, N_PAPER,  er_c);

    // 4-6: relations. r0: feat Oa_b -> A_ws. r1: feat Op_b -> Oa_b (P_a dead).
    // r2: feat Op_b -> Op_b (chunk-wise in-place; chunk cols dead after their
    // aggregate pass).
    const int* rsrc[3]     = {w_src, wb_src, c_src};
    const int* rdst[3]     = {w_dst, wb_dst, c_dst};
    const float* rel_el[3] = {el_w, el_p, el_p};
    const float* rel_er[3] = {er_w, er_wb, er_c};
    const bf16* rfeat[3]   = {Oa_b, Op_b, Op_b};
    bf16* rout[3]          = {A_ws, Oa_b, Op_b};
    int elB = (NEDGE * NHEAD + 255) / 256;
    int agB = NEDGE / 16;
    int rcB = (N_PAPER * 16 + 255) / 256;
    for (int r = 0; r < 3; ++r) {
        hipMemsetAsync(ssum, 0, 400000 * sizeof(float), stream);
        edge_logits<<<elB, 256, 0, stream>>>(rsrc[r], rdst[r], rel_el[r], rel_er[r],
                                             ssum, NEDGE);
        for (int c = 0; c < 4; ++c) {
            int cb = c * 64;
            hipMemsetAsync(ftc, 0, (size_t)N_PAPER * 64 * sizeof(float), stream);
            edge_aggregate_chunk<<<agB, 256, 0, stream>>>(
                rsrc[r], rdst[r], rel_el[r], rel_er[r], ssum, rfeat[r], ftc, NEDGE, cb);
            relu_cast_chunk<<<rcB, 256, 0, stream>>>(ftc, rout[r], N_PAPER, cb);
        }
    }
    // el/er/ssum/ftc dead -> X region becomes a bf16 node slot.

    // 7: rf_written_by = r_written_by(Oa_b) @ W_rel_wb -> X (bf16)
    gemm64<0, bf16, bf16><<<ggrid, gblk, 0, stream>>>(Oa_b, W_rel_wb, N_AUTHOR, X, nullptr, nullptr, nullptr);
    // 8: author gated residual (f32 feats path) -> Oa_f FINAL (overwrites Oa_b
    //    scratch, consumed in step 7; gemm never reads C)
    gemm64<2, float, float><<<ggrid, gblk, 0, stream>>>(feats_a, W_res_a, N_AUTHOR, Oa_f, b_res_a, X, rw_a);
    // 9: fused paper macro (rf_writes/rf_cites/node_paper + semantic attn) -> X
    dim3 fgrid((N_PAPER + 63) / 64, NHEAD);
    rf_fuse_head<<<fgrid, gblk, 0, stream>>>(A_ws, Op_b, feats_p,
                                             W_rel_w, W_rel_c, W_node_p, attn_mac,
                                             X, N_PAPER);
    // 10: paper gated residual -> Op_f FINAL (overwrites Op_b scratch, consumed
    //     in step 9)
    gemm64<2, float, float><<<ggrid, gblk, 0, stream>>>(feats_p, W_res_p, N_PAPER, Op_f, b_res_p, X, rw_p);
}

// Round 7
// 4903.091 us; speedup vs baseline: 1.1204x; 1.1204x over previous
//
#include <hip/hip_runtime.h>
#include <hip/hip_bf16.h>
#include <type_traits>

// HGConv layer: micro (per-relation GAT) + macro (semantic attention) + gated residual.
// I/O: float32 (verified round 6). Internals: bf16 matrices, f32 accumulation.
// Round 7: all dense GEMMs on MFMA (16x16x32 bf16, 128x128 tiles); rf_fuse_head
// replaced by score-vector algebra + fused epilogue in the rf_cites GEMM.

#define N_AUTHOR 50000
#define N_PAPER  50000
#define NEDGE    400000
#define KDIM     256
#define NHEAD    8
#define SLOPE    0.2f

using bf16 = __hip_bfloat16;
typedef __attribute__((ext_vector_type(8))) short short8;
typedef __attribute__((ext_vector_type(4))) float float4e;

__device__ __forceinline__ float us2f(unsigned short u) {
    return __uint_as_float(((unsigned int)u) << 16);
}
__device__ __forceinline__ float fin(float v) {   // 0 if NaN/Inf
    return (((__float_as_uint(v) >> 23) & 0xFF) != 0xFF) ? v : 0.f;
}
__device__ __forceinline__ unsigned short f2bu(float f) {
    f = fin(f);
    bf16 h = __float2bfloat16(f);
    return *reinterpret_cast<unsigned short*>(&h);
}
__device__ __forceinline__ int clampi(int v, int hi) {
    return v < 0 ? 0 : (v >= hi ? hi - 1 : v);
}

__global__ void fill_marker(float* __restrict__ out, int total, float c)
{
    int i = blockIdx.x * blockDim.x + threadIdx.x;
    if (i < total) out[i] = c;
}

// ---------------------------------------------------------------------------
// W[256k][256n] f32  ->  BT[256n][256k] bf16  (pre-transpose for MFMA B-frags)
// ---------------------------------------------------------------------------
__global__ void prep_bt(const float* __restrict__ W, bf16* __restrict__ BT)
{
    int n = blockIdx.x, k = threadIdx.x;
    reinterpret_cast<unsigned short*>(BT)[n * KDIM + k] = f2bu(W[k * KDIM + n]);
}

// ---------------------------------------------------------------------------
// MFMA GEMM: C[M x 256] = A[M x 256] @ B (BT = B^T bf16 [n][k]), f32 acc.
// 128x128 tile, BK=32, 256 threads = 4 waves (2x2 of 64x64), 4x4 frags/wave.
// MODE 0: C(bf16) = acc
// MODE 1: C(bf16) = sc_w[n,h]*rfw + sc_c[n,h]*acc      (paper fusion epilogue)
// MODE 2: C(f32)  = sig(g)*other(bf16) + (1-sig(g))*(acc + bias)  (residual)
// Fragment layouts (HW-verified per guide): A[m=lane&15][k=quad*8+j],
// B[k=quad*8+j][n=lane&15], C/D row=quad*4+reg, col=lane&15.
// ---------------------------------------------------------------------------
template<int MODE, typename TA>
__global__ __launch_bounds__(256) void mfma_gemm(
    const TA* __restrict__ A, const bf16* __restrict__ BT, int M,
    void* __restrict__ Cout,
    const float* __restrict__ bias, const bf16* __restrict__ other,
    const float* __restrict__ gate,
    const bf16* __restrict__ rfw, const float* __restrict__ sc_w,
    const float* __restrict__ sc_c)
{
    __shared__ short As[128 * 40];   // [row][k], pad 32->40 (2-way banks max)
    __shared__ short Bs[128 * 40];   // [n][k]
    const int tid = threadIdx.x;
    const int lane = tid & 63, wave = tid >> 6;
    const int wm = wave >> 1, wn = wave & 1;
    const int rowBase = blockIdx.y * 128;
    const int colBase = blockIdx.x * 128;

    float4e acc[4][4];
    #pragma unroll
    for (int i = 0; i < 4; ++i)
        #pragma unroll
        for (int j = 0; j < 4; ++j) {
            float4e z = {0.f, 0.f, 0.f, 0.f};
            acc[i][j] = z;
        }

    const int srow = tid >> 2;          // 0..63  (staging row)
    const int sq = (tid & 3) << 3;      // 0,8,16,24 (staging k offset)

    for (int kt = 0; kt < KDIM; kt += 32) {
        // ---- stage A tile (128 rows x 32 k) ----
        #pragma unroll
        for (int p = 0; p < 2; ++p) {
            int r = srow + p * 64;
            int gr = rowBase + r;
            short8 v = {0, 0, 0, 0, 0, 0, 0, 0};
            if (gr < M) {
                if constexpr (std::is_same<TA, float>::value) {
                    const float* ap = A + (size_t)gr * KDIM + kt + sq;
                    float4 x = *reinterpret_cast<const float4*>(ap);
                    float4 y = *reinterpret_cast<const float4*>(ap + 4);
                    v[0] = (short)f2bu(x.x); v[1] = (short)f2bu(x.y);
                    v[2] = (short)f2bu(x.z); v[3] = (short)f2bu(x.w);
                    v[4] = (short)f2bu(y.x); v[5] = (short)f2bu(y.y);
                    v[6] = (short)f2bu(y.z); v[7] = (short)f2bu(y.w);
                } else {
                    v = *reinterpret_cast<const short8*>(
                        reinterpret_cast<const short*>(A) + (size_t)gr * KDIM + kt + sq);
                }
            }
            *reinterpret_cast<short8*>(&As[r * 40 + sq]) = v;
        }
        // ---- stage B tile (128 n x 32 k) from BT[n][k] ----
        #pragma unroll
        for (int p = 0; p < 2; ++p) {
            int n = srow + p * 64;
            short8 v = *reinterpret_cast<const short8*>(
                reinterpret_cast<const short*>(BT) + (size_t)(colBase + n) * KDIM + kt + sq);
            *reinterpret_cast<short8*>(&Bs[n * 40 + sq]) = v;
        }
        __syncthreads();

        short8 af[4], bg[4];
        #pragma unroll
        for (int i = 0; i < 4; ++i)
            af[i] = *reinterpret_cast<const short8*>(
                &As[(wm * 64 + i * 16 + (lane & 15)) * 40 + ((lane >> 4) << 3)]);
        #pragma unroll
        for (int j = 0; j < 4; ++j)
            bg[j] = *reinterpret_cast<const short8*>(
                &Bs[(wn * 64 + j * 16 + (lane & 15)) * 40 + ((lane >> 4) << 3)]);
        #pragma unroll
        for (int i = 0; i < 4; ++i)
            #pragma unroll
            for (int j = 0; j < 4; ++j)
                acc[i][j] = __builtin_amdgcn_mfma_f32_16x16x32_bf16(
                    af[i], bg[j], acc[i][j], 0, 0, 0);
        __syncthreads();
    }

    float al = 0.f;
    if constexpr (MODE == 2) al = 1.f / (1.f + expf(-gate[0]));

    #pragma unroll
    for (int i = 0; i < 4; ++i) {
        int r0 = rowBase + wm * 64 + i * 16 + ((lane >> 4) << 2);
        #pragma unroll
        for (int j = 0; j < 4; ++j) {
            int col = colBase + wn * 64 + j * 16 + (lane & 15);
            #pragma unroll
            for (int reg = 0; reg < 4; ++reg) {
                int row = r0 + reg;
                if (row < M) {
                    size_t idx = (size_t)row * KDIM + col;
                    float v = acc[i][j][reg];
                    if constexpr (MODE == 0) {
                        reinterpret_cast<unsigned short*>(Cout)[idx] = f2bu(v);
                    } else if constexpr (MODE == 1) {
                        int h = col >> 5;
                        size_t si = (size_t)row * NHEAD + h;
                        float f = sc_w[si] * us2f(reinterpret_cast<const unsigned short*>(rfw)[idx])
                                + sc_c[si] * v;
                        reinterpret_cast<unsigned short*>(Cout)[idx] = f2bu(f);
                    } else {
                        float of = us2f(reinterpret_cast<const unsigned short*>(other)[idx]);
                        reinterpret_cast<float*>(Cout)[idx] =
                            fin(al * of + (1.f - al) * (v + bias[col]));
                    }
                }
            }
        }
    }
}

// ---------------------------------------------------------------------------
// Per-node per-head attention dot (micro): out[n*8+k] = proj[n,k*32:+32]·attn[k*64+off:+32]
// ---------------------------------------------------------------------------
__global__ void head_dot(const bf16* __restrict__ proj, const float* __restrict__ attn,
                         int off, int N, float* __restrict__ out)
{
    int gid = blockIdx.x * blockDim.x + threadIdx.x;
    if (gid >= N * NHEAD) return;
    int n = gid >> 3, k = gid & 7;
    const unsigned short* p =
        reinterpret_cast<const unsigned short*>(proj) + (size_t)n * KDIM + k * 32;
    const float* a = attn + k * 64 + off;
    float s = 0.f;
    #pragma unroll
    for (int d0 = 0; d0 < 32; d0 += 4) {
        ushort4 pv = *reinterpret_cast<const ushort4*>(p + d0);
        float4 av = *reinterpret_cast<const float4*>(a + d0);
        s += us2f(pv.x) * av.x + us2f(pv.y) * av.y
           + us2f(pv.z) * av.z + us2f(pv.w) * av.w;
    }
    out[gid] = fin(s);
}

// ---------------------------------------------------------------------------
// Edge pass A: ssum[dst,k] += exp(leakyrelu(el[src]+er[dst])), arg clamped at 30.
// ---------------------------------------------------------------------------
__global__ void edge_logits(const int* __restrict__ src, const int* __restrict__ dst,
                            const float* __restrict__ el, const float* __restrict__ er,
                            float* __restrict__ ssum, int E)
{
    int gid = blockIdx.x * blockDim.x + threadIdx.x;
    if (gid >= E * NHEAD) return;
    int e = gid >> 3, k = gid & 7;
    int s = clampi(src[e], N_PAPER), d = clampi(dst[e], N_PAPER);
    float v = el[s * NHEAD + k] + er[d * NHEAD + k];
    v = v > 0.f ? v : SLOPE * v;
    atomicAdd(&ssum[d * NHEAD + k], fin(expf(fminf(v, 30.f))));
}

// ---------------------------------------------------------------------------
// Edge pass B (128-col chunks): ftc[dst, chunk] += feat[src, chunk] * a.
// 8 edges/block x 32 lanes; lane covers 4 cols.
// ---------------------------------------------------------------------------
__global__ __launch_bounds__(256) void edge_aggregate_chunk(
    const int* __restrict__ src, const int* __restrict__ dst,
    const float* __restrict__ el, const float* __restrict__ er,
    const float* __restrict__ ssum, const bf16* __restrict__ feat,
    float* __restrict__ ftc, int E, int cb)
{
    int t = threadIdx.x;
    int e = blockIdx.x * 8 + (t >> 5);
    if (e >= E) return;
    int l = t & 31;
    int col = cb + l * 4;
    int head = col >> 5;
    int s = clampi(src[e], N_PAPER), d = clampi(dst[e], N_PAPER);
    float v = el[s * NHEAD + head] + er[d * NHEAD + head];
    v = v > 0.f ? v : SLOPE * v;
    float a = expf(fminf(v, 30.f)) / fmaxf(ssum[d * NHEAD + head], 1e-20f);
    a = fin(a);
    ushort4 fv = *reinterpret_cast<const ushort4*>(
        reinterpret_cast<const unsigned short*>(feat) + (size_t)s * KDIM + col);
    float* o = ftc + (size_t)d * 128 + l * 4;
    atomicAdd(o + 0, fin(us2f(fv.x) * a));
    atomicAdd(o + 1, fin(us2f(fv.y) * a));
    atomicAdd(o + 2, fin(us2f(fv.z) * a));
    atomicAdd(o + 3, fin(us2f(fv.w) * a));
}

// ---------------------------------------------------------------------------
// relu + cast of one 128-col chunk -> bf16 internal
// ---------------------------------------------------------------------------
__global__ void relu_cast_chunk(const float* __restrict__ ftc, bf16* __restrict__ out,
                                int N, int cb)
{
    int gid = blockIdx.x * blockDim.x + threadIdx.x;
    if (gid >= N * 32) return;
    int n = gid >> 5, jj = (gid & 31) * 4;
    float4 v = *reinterpret_cast<const float4*>(ftc + (size_t)n * 128 + jj);
    ushort4 o;
    o.x = f2bu(fmaxf(v.x, 0.f)); o.y = f2bu(fmaxf(v.y, 0.f));
    o.z = f2bu(fmaxf(v.z, 0.f)); o.w = f2bu(fmaxf(v.w, 0.f));
    *reinterpret_cast<ushort4*>(
        reinterpret_cast<unsigned short*>(out) + (size_t)n * KDIM + cb + jj) = o;
}

// ---------------------------------------------------------------------------
// Score vectors: v[which][h][k] = sum_d Wsrc[k, h*32+d] * attn[h*64 + aoff + d]
// which 0 = W_rel_w (aoff 32), 1 = W_rel_c (aoff 32), 2 = W_node_p (aoff 0).
// ---------------------------------------------------------------------------
__global__ void prep_v(const float* __restrict__ Ww, const float* __restrict__ Wc,
                       const float* __restrict__ Wn, const float* __restrict__ attn,
                       float* __restrict__ vbuf)
{
    int id = blockIdx.x * blockDim.x + threadIdx.x;
    if (id >= 3 * 2048) return;
    int which = id >> 11;
    int rem = id & 2047;
    int h = rem >> 8, k = rem & 255;
    const float* Wsrc = which == 0 ? Ww : (which == 1 ? Wc : Wn);
    int aoff = which == 2 ? 0 : 32;
    float s = 0.f;
    #pragma unroll 8
    for (int d = 0; d < 32; ++d)
        s += Wsrc[(size_t)k * KDIM + h * 32 + d] * attn[h * 64 + aoff + d];
    vbuf[which * 2048 + h * 256 + k] = fin(s);
}

// ---------------------------------------------------------------------------
// Skinny dot: out[n*8+h] = A[n,:256] · v[h,:256]
// ---------------------------------------------------------------------------
template<typename T>
__global__ void macro_dot(const T* __restrict__ A, const float* __restrict__ v0,
                          float* __restrict__ out, int N)
{
    int id = blockIdx.x * blockDim.x + threadIdx.x;
    if (id >= N * NHEAD) return;
    int n = id >> 3, h = id & 7;
    const float* vh = v0 + h * 256;
    float s = 0.f;
    if constexpr (std::is_same<T, float>::value) {
        const float* row = A + (size_t)n * KDIM;
        for (int k = 0; k < KDIM; k += 4) {
            float4 a = *reinterpret_cast<const float4*>(row + k);
            float4 b = *reinterpret_cast<const float4*>(vh + k);
            s += a.x * b.x + a.y * b.y + a.z * b.z + a.w * b.w;
        }
    } else {
        const unsigned short* row =
            reinterpret_cast<const unsigned short*>(A) + (size_t)n * KDIM;
        for (int k = 0; k < KDIM; k += 4) {
            ushort4 a = *reinterpret_cast<const ushort4*>(row + k);
            float4 b = *reinterpret_cast<const float4*>(vh + k);
            s += us2f(a.x) * b.x + us2f(a.y) * b.y + us2f(a.z) * b.z + us2f(a.w) * b.w;
        }
    }
    out[id] = fin(s);
}

// ---------------------------------------------------------------------------
// Semantic-attention softmax over R=2 relations per (node, head).
// ---------------------------------------------------------------------------
__global__ void score_kernel(const float* __restrict__ dotL, const float* __restrict__ dotW,
                             const float* __restrict__ dotC,
                             float* __restrict__ ow, float* __restrict__ oc, int total)
{
    int i = blockIdx.x * blockDim.x + threadIdx.x;
    if (i >= total) return;
    float sw = dotL[i] + dotW[i]; sw = sw > 0.f ? sw : SLOPE * sw;
    float sc = dotL[i] + dotC[i]; sc = sc > 0.f ? sc : SLOPE * sc;
    float m = fmaxf(sw, sc);
    float ew = expf(sw - m), ec = expf(sc - m);
    float inv = 1.f / (ew + ec);
    ow[i] = fin(ew * inv);
    oc[i] = fin(ec * inv);
}

// ---------------------------------------------------------------------------
extern "C" void kernel_launch(void* const* d_in, const int* in_sizes, int n_in,
                              void* d_out, int out_size, void* d_ws, size_t ws_size,
                              hipStream_t stream)
{
    static const int expected[24] = {
        12800000, 12800000, 65536, 65536, 512, 512, 65536, 65536,
        65536, 65536, 65536, 512, 65536, 256, 65536, 256, 1, 1,
        400000, 400000, 400000, 400000, 400000, 400000};
    float marker = 0.f;
    if (n_in != 24) marker = 500.f;
    else {
        for (int i = 0; i < 24; ++i)
            if (in_sizes[i] != expected[i]) { marker = 200.f + 8.f * i; break; }
    }
    if (marker == 0.f && out_size != 25600000) marker = 600.f + (float)(out_size / 1000000);
    if (marker == 0.f && ws_size < 51200000ull) marker = 1000.f + (float)(ws_size / 1000000ull);
    if (marker != 0.f) {
        fill_marker<<<(out_size + 255) / 256, 256, 0, stream>>>((float*)d_out, out_size, marker);
        return;
    }

    const float* feats_a  = (const float*)d_in[0];
    const float* feats_p  = (const float*)d_in[1];
    const float* W_mic_a  = (const float*)d_in[2];
    const float* W_mic_p  = (const float*)d_in[3];
    const float* attn_a   = (const float*)d_in[4];
    const float* attn_p   = (const float*)d_in[5];
    // d_in[6] = W_macro_node_author: unused (author macro passthrough)
    const float* W_node_p = (const float*)d_in[7];
    const float* W_rel_w  = (const float*)d_in[8];
    const float* W_rel_wb = (const float*)d_in[9];
    const float* W_rel_c  = (const float*)d_in[10];
    const float* attn_mac = (const float*)d_in[11];
    const float* W_res_a  = (const float*)d_in[12];
    const float* b_res_a  = (const float*)d_in[13];
    const float* W_res_p  = (const float*)d_in[14];
    const float* b_res_p  = (const float*)d_in[15];
    const float* rw_a     = (const float*)d_in[16];
    const float* rw_p     = (const float*)d_in[17];
    const int* w_src  = (const int*)d_in[18];
    const int* w_dst  = (const int*)d_in[19];
    const int* wb_src = (const int*)d_in[20];
    const int* wb_dst = (const int*)d_in[21];
    const int* c_src  = (const int*)d_in[22];
    const int* c_dst  = (const int*)d_in[23];

    const int NB = N_PAPER * KDIM;            // 12.8M elems
    // ---- d_out (f32, 102.4MB): [author 51.2MB][paper 51.2MB] ----
    float* Oa_f = (float*)d_out;
    float* Op_f = Oa_f + NB;
    bf16* Oa_b = (bf16*)d_out;                // P_a -> r_written_by (lower author)
    bf16* Op_b = (bf16*)Op_f;                 // P_p -> r_cites     (lower paper)
    char* au_up = (char*)d_out + 25600000;    // author upper 25.6MB scratch
    float* ftc  = (float*)au_up;              // relations: 50000x128 f32 chunk
    bf16*  Sa   = (bf16*)au_up;               // macro: rf_writes (25.6MB)
    bf16*  BTa0 = (bf16*)au_up;               // P5 BT (after Sa dead)
    bf16*  BTa1 = BTa0 + 65536;               // P6 BT
    char* pu = (char*)d_out + 76800000;       // paper upper 25.6MB scratch
    float* dotW = (float*)pu;                 // 5 x 400,000 f32 + vbuf
    float* dotC = dotW + 400000;
    float* dotL = dotW + 800000;
    float* sc_w = dotW + 1200000;
    float* sc_c = dotW + 1600000;
    float* vbuf = dotW + 2000000;             // 6144 f32
    bf16* BT0 = (bf16*)(pu + 10000000);       // early BT slots (128KB each)
    bf16* BT1 = BT0 + 65536;
    bf16* BT2 = BT1 + 65536;
    bf16* BT3 = BT2 + 65536;
    // ---- d_ws (51.2e6 B): [A_ws 25.6MB][X 25.6MB] ----
    bf16* A_ws = (bf16*)d_ws;                 // r_writes -> fused_paper
    bf16* BTw  = (bf16*)d_ws;                 // P7 BT (after fused dead)
    char* Xb   = (char*)d_ws + 25600000;
    float* el_w  = (float*)Xb;                // edge-stage arrays
    float* er_w  = el_w + 400000;
    float* el_p  = el_w + 800000;
    float* er_wb = el_w + 1200000;
    float* er_c  = el_w + 1600000;
    float* ssum  = el_w + 2000000;
    bf16*  Xslot = (bf16*)Xb;                 // macro: rf_written_by (25.6MB)

    dim3 mg(2, (N_PAPER + 127) / 128);        // MFMA GEMM grid (N=256 fixed)
    int hdB = (N_PAPER * NHEAD + 255) / 256;

    // ---- 1: micro projections (MFMA) ----
    prep_bt<<<256, 256, 0, stream>>>(W_mic_a, BT0);
    prep_bt<<<256, 256, 0, stream>>>(W_mic_p, BT1);
    mfma_gemm<0, float><<<mg, 256, 0, stream>>>(feats_a, BT0, N_AUTHOR, Oa_b,
        nullptr, nullptr, nullptr, nullptr, nullptr, nullptr);
    mfma_gemm<0, float><<<mg, 256, 0, stream>>>(feats_p, BT1, N_PAPER, Op_b,
        nullptr, nullptr, nullptr, nullptr, nullptr, nullptr);

    // ---- 2: micro attention dots ----
    head_dot<<<hdB, 256, 0, stream>>>(Oa_b, attn_a, 0,  N_AUTHOR, el_w);
    head_dot<<<hdB, 256, 0, stream>>>(Op_b, attn_a, 32, N_PAPER,  er_w);
    head_dot<<<hdB, 256, 0, stream>>>(Op_b, attn_p, 0,  N_PAPER,  el_p);
    head_dot<<<hdB, 256, 0, stream>>>(Oa_b, attn_p, 32, N_AUTHOR, er_wb);
    head_dot<<<hdB, 256, 0, stream>>>(Op_b, attn_p, 32, N_PAPER,  er_c);

    // ---- 3: relations (edge softmax + aggregate; ftc chunk in author upper) ----
    const int* rsrc[3]     = {w_src, wb_src, c_src};
    const int* rdst[3]     = {w_dst, wb_dst, c_dst};
    const float* rel_el[3] = {el_w, el_p, el_p};
    const float* rel_er[3] = {er_w, er_wb, er_c};
    const bf16* rfeat[3]   = {Oa_b, Op_b, Op_b};
    bf16* rout[3]          = {A_ws, Oa_b, Op_b};
    int elB = (NEDGE * NHEAD + 255) / 256;
    int agB = NEDGE / 8;
    int rcB = (N_PAPER * 32 + 255) / 256;
    for (int r = 0; r < 3; ++r) {
        hipMemsetAsync(ssum, 0, 400000 * sizeof(float), stream);
        edge_logits<<<elB, 256, 0, stream>>>(rsrc[r], rdst[r], rel_el[r], rel_er[r],
                                             ssum, NEDGE);
        for (int c = 0; c < 2; ++c) {
            int cb = c * 128;
            hipMemsetAsync(ftc, 0, (size_t)N_PAPER * 128 * sizeof(float), stream);
            edge_aggregate_chunk<<<agB, 256, 0, stream>>>(
                rsrc[r], rdst[r], rel_el[r], rel_er[r], ssum, rfeat[r], ftc, NEDGE, cb);
            relu_cast_chunk<<<rcB, 256, 0, stream>>>(ftc, rout[r], N_PAPER, cb);
        }
    }
    // A_ws=r_writes, Oa_b=r_written_by, Op_b=r_cites; edge arrays dead.

    // ---- 4: macro scores via vector algebra (node_paper never materialized) ----
    prep_v<<<24, 256, 0, stream>>>(W_rel_w, W_rel_c, W_node_p, attn_mac, vbuf);
    macro_dot<bf16><<<hdB, 256, 0, stream>>>(A_ws, vbuf,        dotW, N_PAPER);
    macro_dot<bf16><<<hdB, 256, 0, stream>>>(Op_b, vbuf + 2048, dotC, N_PAPER);
    macro_dot<float><<<hdB, 256, 0, stream>>>(feats_p, vbuf + 4096, dotL, N_PAPER);
    score_kernel<<<hdB, 256, 0, stream>>>(dotL, dotW, dotC, sc_w, sc_c, N_PAPER * NHEAD);

    // ---- 5: rf_writes = r_writes @ W_rel_w -> Sa (author upper; ftc dead) ----
    prep_bt<<<256, 256, 0, stream>>>(W_rel_w, BT2);
    mfma_gemm<0, bf16><<<mg, 256, 0, stream>>>(A_ws, BT2, N_PAPER, Sa,
        nullptr, nullptr, nullptr, nullptr, nullptr, nullptr);
    // ---- 6: fused_paper = sc_w*rf_writes + sc_c*(r_cites @ W_rel_c) -> A_ws ----
    prep_bt<<<256, 256, 0, stream>>>(W_rel_c, BT3);
    mfma_gemm<1, bf16><<<mg, 256, 0, stream>>>(Op_b, BT3, N_PAPER, A_ws,
        nullptr, nullptr, nullptr, Sa, sc_w, sc_c);
    // ---- 7: paper gated residual -> Op_f FINAL (overwrites Op_b + paper upper) ----
    prep_bt<<<256, 256, 0, stream>>>(W_res_p, BTa0);   // author upper (Sa dead)
    mfma_gemm<2, float><<<mg, 256, 0, stream>>>(feats_p, BTa0, N_PAPER, Op_f,
        b_res_p, A_ws, rw_p, nullptr, nullptr, nullptr);
    // ---- 8: rf_written_by = r_written_by @ W_rel_wb -> Xslot ----
    prep_bt<<<256, 256, 0, stream>>>(W_rel_wb, BTa1);
    mfma_gemm<0, bf16><<<mg, 256, 0, stream>>>(Oa_b, BTa1, N_AUTHOR, Xslot,
        nullptr, nullptr, nullptr, nullptr, nullptr, nullptr);
    // ---- 9: author gated residual -> Oa_f FINAL (BT in A_ws; fused dead) ----
    prep_bt<<<256, 256, 0, stream>>>(W_res_a, BTw);
    mfma_gemm<2, float><<<mg, 256, 0, stream>>>(feats_a, BTw, N_AUTHOR, Oa_f,
        b_res_a, Xslot, rw_a, nullptr, nullptr, nullptr);
}

// Round 8
// 1310.118 us; speedup vs baseline: 4.1930x; 3.7425x over previous
//
#include <hip/hip_runtime.h>
#include <hip/hip_bf16.h>
#include <type_traits>

// HGConv layer: micro (per-relation GAT) + macro (semantic attention) + gated residual.
// I/O: float32 (verified round 6). Internals: bf16 matrices, f32 accumulation.
// Round 8: edge stage scatter->gather via on-device CSR (round 7 spent 4.06ms of
// 4.9ms in atomic scatter w/ 800MB write amplification per dispatch).

#define N_AUTHOR 50000
#define N_PAPER  50000
#define NEDGE    400000
#define KDIM     256
#define NHEAD    8
#define SLOPE    0.2f

using bf16 = __hip_bfloat16;
typedef __attribute__((ext_vector_type(8))) short short8;
typedef __attribute__((ext_vector_type(4))) float float4e;

__device__ __forceinline__ float us2f(unsigned short u) {
    return __uint_as_float(((unsigned int)u) << 16);
}
__device__ __forceinline__ float fin(float v) {   // 0 if NaN/Inf
    return (((__float_as_uint(v) >> 23) & 0xFF) != 0xFF) ? v : 0.f;
}
__device__ __forceinline__ unsigned short f2bu(float f) {
    f = fin(f);
    bf16 h = __float2bfloat16(f);
    return *reinterpret_cast<unsigned short*>(&h);
}
__device__ __forceinline__ int clampi(int v, int hi) {
    return v < 0 ? 0 : (v >= hi ? hi - 1 : v);
}

__global__ void fill_marker(float* __restrict__ out, int total, float c)
{
    int i = blockIdx.x * blockDim.x + threadIdx.x;
    if (i < total) out[i] = c;
}

// ---------------------------------------------------------------------------
// W[256k][256n] f32  ->  BT[256n][256k] bf16  (pre-transpose for MFMA B-frags)
// ---------------------------------------------------------------------------
__global__ void prep_bt(const float* __restrict__ W, bf16* __restrict__ BT)
{
    int n = blockIdx.x, k = threadIdx.x;
    reinterpret_cast<unsigned short*>(BT)[n * KDIM + k] = f2bu(W[k * KDIM + n]);
}

// ---------------------------------------------------------------------------
// MFMA GEMM: C[M x 256] = A[M x 256] @ B (BT = B^T bf16 [n][k]), f32 acc.
// 128x128 tile, BK=32, 256 threads = 4 waves (2x2 of 64x64), 4x4 frags/wave.
// MODE 0: C(bf16) = acc
// MODE 1: C(bf16) = sc_w[n,h]*rfw + sc_c[n,h]*acc      (paper fusion epilogue)
// MODE 2: C(f32)  = sig(g)*other(bf16) + (1-sig(g))*(acc + bias)  (residual)
// ---------------------------------------------------------------------------
template<int MODE, typename TA>
__global__ __launch_bounds__(256) void mfma_gemm(
    const TA* __restrict__ A, const bf16* __restrict__ BT, int M,
    void* __restrict__ Cout,
    const float* __restrict__ bias, const bf16* __restrict__ other,
    const float* __restrict__ gate,
    const bf16* __restrict__ rfw, const float* __restrict__ sc_w,
    const float* __restrict__ sc_c)
{
    __shared__ short As[128 * 40];   // [row][k], pad 32->40
    __shared__ short Bs[128 * 40];   // [n][k]
    const int tid = threadIdx.x;
    const int lane = tid & 63, wave = tid >> 6;
    const int wm = wave >> 1, wn = wave & 1;
    const int rowBase = blockIdx.y * 128;
    const int colBase = blockIdx.x * 128;

    float4e acc[4][4];
    #pragma unroll
    for (int i = 0; i < 4; ++i)
        #pragma unroll
        for (int j = 0; j < 4; ++j) {
            float4e z = {0.f, 0.f, 0.f, 0.f};
            acc[i][j] = z;
        }

    const int srow = tid >> 2;          // 0..63
    const int sq = (tid & 3) << 3;      // 0,8,16,24

    for (int kt = 0; kt < KDIM; kt += 32) {
        #pragma unroll
        for (int p = 0; p < 2; ++p) {
            int r = srow + p * 64;
            int gr = rowBase + r;
            short8 v = {0, 0, 0, 0, 0, 0, 0, 0};
            if (gr < M) {
                if constexpr (std::is_same<TA, float>::value) {
                    const float* ap = A + (size_t)gr * KDIM + kt + sq;
                    float4 x = *reinterpret_cast<const float4*>(ap);
                    float4 y = *reinterpret_cast<const float4*>(ap + 4);
                    v[0] = (short)f2bu(x.x); v[1] = (short)f2bu(x.y);
                    v[2] = (short)f2bu(x.z); v[3] = (short)f2bu(x.w);
                    v[4] = (short)f2bu(y.x); v[5] = (short)f2bu(y.y);
                    v[6] = (short)f2bu(y.z); v[7] = (short)f2bu(y.w);
                } else {
                    v = *reinterpret_cast<const short8*>(
                        reinterpret_cast<const short*>(A) + (size_t)gr * KDIM + kt + sq);
                }
            }
            *reinterpret_cast<short8*>(&As[r * 40 + sq]) = v;
        }
        #pragma unroll
        for (int p = 0; p < 2; ++p) {
            int n = srow + p * 64;
            short8 v = *reinterpret_cast<const short8*>(
                reinterpret_cast<const short*>(BT) + (size_t)(colBase + n) * KDIM + kt + sq);
            *reinterpret_cast<short8*>(&Bs[n * 40 + sq]) = v;
        }
        __syncthreads();

        short8 af[4], bg[4];
        #pragma unroll
        for (int i = 0; i < 4; ++i)
            af[i] = *reinterpret_cast<const short8*>(
                &As[(wm * 64 + i * 16 + (lane & 15)) * 40 + ((lane >> 4) << 3)]);
        #pragma unroll
        for (int j = 0; j < 4; ++j)
            bg[j] = *reinterpret_cast<const short8*>(
                &Bs[(wn * 64 + j * 16 + (lane & 15)) * 40 + ((lane >> 4) << 3)]);
        #pragma unroll
        for (int i = 0; i < 4; ++i)
            #pragma unroll
            for (int j = 0; j < 4; ++j)
                acc[i][j] = __builtin_amdgcn_mfma_f32_16x16x32_bf16(
                    af[i], bg[j], acc[i][j], 0, 0, 0);
        __syncthreads();
    }

    float al = 0.f;
    if constexpr (MODE == 2) al = 1.f / (1.f + expf(-gate[0]));

    #pragma unroll
    for (int i = 0; i < 4; ++i) {
        int r0 = rowBase + wm * 64 + i * 16 + ((lane >> 4) << 2);
        #pragma unroll
        for (int j = 0; j < 4; ++j) {
            int col = colBase + wn * 64 + j * 16 + (lane & 15);
            #pragma unroll
            for (int reg = 0; reg < 4; ++reg) {
                int row = r0 + reg;
                if (row < M) {
                    size_t idx = (size_t)row * KDIM + col;
                    float v = acc[i][j][reg];
                    if constexpr (MODE == 0) {
                        reinterpret_cast<unsigned short*>(Cout)[idx] = f2bu(v);
                    } else if constexpr (MODE == 1) {
                        int h = col >> 5;
                        size_t si = (size_t)row * NHEAD + h;
                        float f = sc_w[si] * us2f(reinterpret_cast<const unsigned short*>(rfw)[idx])
                                + sc_c[si] * v;
                        reinterpret_cast<unsigned short*>(Cout)[idx] = f2bu(f);
                    } else {
                        float of = us2f(reinterpret_cast<const unsigned short*>(other)[idx]);
                        reinterpret_cast<float*>(Cout)[idx] =
                            fin(al * of + (1.f - al) * (v + bias[col]));
                    }
                }
            }
        }
    }
}

// ---------------------------------------------------------------------------
// Per-node per-head attention dot (micro)
// ---------------------------------------------------------------------------
__global__ void head_dot(const bf16* __restrict__ proj, const float* __restrict__ attn,
                         int off, int N, float* __restrict__ out)
{
    int gid = blockIdx.x * blockDim.x + threadIdx.x;
    if (gid >= N * NHEAD) return;
    int n = gid >> 3, k = gid & 7;
    const unsigned short* p =
        reinterpret_cast<const unsigned short*>(proj) + (size_t)n * KDIM + k * 32;
    const float* a = attn + k * 64 + off;
    float s = 0.f;
    #pragma unroll
    for (int d0 = 0; d0 < 32; d0 += 4) {
        ushort4 pv = *reinterpret_cast<const ushort4*>(p + d0);
        float4 av = *reinterpret_cast<const float4*>(a + d0);
        s += us2f(pv.x) * av.x + us2f(pv.y) * av.y
           + us2f(pv.z) * av.z + us2f(pv.w) * av.w;
    }
    out[gid] = fin(s);
}

// ---------------------------------------------------------------------------
// CSR build: histogram -> exclusive scan -> scatter src-ids into CSR order.
// ---------------------------------------------------------------------------
__global__ void edge_hist(const int* __restrict__ dst, int* __restrict__ cnt, int E)
{
    int e = blockIdx.x * blockDim.x + threadIdx.x;
    if (e < E) atomicAdd(&cnt[clampi(dst[e], N_PAPER)], 1);
}

__global__ __launch_bounds__(1024) void scan_off(const int* __restrict__ cnt,
                                                 int* __restrict__ off,
                                                 int* __restrict__ woff, int N)
{
    __shared__ int buf[1024];
    __shared__ int carry;
    if (threadIdx.x == 0) carry = 0;
    __syncthreads();
    for (int base = 0; base < N; base += 1024) {
        int i = base + threadIdx.x;
        int v = (i < N) ? cnt[i] : 0;
        buf[threadIdx.x] = v;
        __syncthreads();
        #pragma unroll
        for (int o = 1; o < 1024; o <<= 1) {
            int t = (threadIdx.x >= o) ? buf[threadIdx.x - o] : 0;
            __syncthreads();
            buf[threadIdx.x] += t;
            __syncthreads();
        }
        int exc = buf[threadIdx.x] - v + carry;
        if (i < N) { off[i] = exc; woff[i] = exc; }
        int total = buf[1023];
        __syncthreads();
        if (threadIdx.x == 0) carry += total;
        __syncthreads();
    }
    if (threadIdx.x == 0) off[N] = carry;
}

__global__ void edge_scatter(const int* __restrict__ src, const int* __restrict__ dst,
                             int* __restrict__ woff, int* __restrict__ gsrc, int E)
{
    int e = blockIdx.x * blockDim.x + threadIdx.x;
    if (e >= E) return;
    int d = clampi(dst[e], N_PAPER);
    int pos = atomicAdd(&woff[d], 1);
    gsrc[pos] = clampi(src[e], N_PAPER);
}

// ---------------------------------------------------------------------------
// GAT gather: one wave per dst node; lane covers 4 cols, head = lane>>3.
// Single pass (linearity): ft = relu( (sum_e ex_e * feat[src_e]) / sum_e ex_e ).
// No atomics; fused softmax + aggregate + relu + bf16 cast.
// ---------------------------------------------------------------------------
__global__ __launch_bounds__(256) void gat_gather(
    const int* __restrict__ off, const int* __restrict__ gsrc,
    const float* __restrict__ el, const float* __restrict__ er,
    const bf16* __restrict__ feat, bf16* __restrict__ out, int N)
{
    int d = blockIdx.x * 4 + (threadIdx.x >> 6);
    if (d >= N) return;
    int lane = threadIdx.x & 63;
    int h = lane >> 3;
    int col = lane * 4;
    float erd = er[d * NHEAD + h];
    int e0 = off[d], e1 = off[d + 1];
    float denom = 0.f, a0 = 0.f, a1 = 0.f, a2 = 0.f, a3 = 0.f;
    for (int e = e0; e < e1; ++e) {
        int s = gsrc[e];
        float v = el[s * NHEAD + h] + erd;
        v = v > 0.f ? v : SLOPE * v;
        float ex = expf(fminf(v, 30.f));
        denom += ex;
        ushort4 fv = *reinterpret_cast<const ushort4*>(
            reinterpret_cast<const unsigned short*>(feat) + (size_t)s * KDIM + col);
        a0 = fmaf(us2f(fv.x), ex, a0); a1 = fmaf(us2f(fv.y), ex, a1);
        a2 = fmaf(us2f(fv.z), ex, a2); a3 = fmaf(us2f(fv.w), ex, a3);
    }
    float inv = 1.f / fmaxf(denom, 1e-20f);
    ushort4 o;
    o.x = f2bu(fmaxf(a0 * inv, 0.f)); o.y = f2bu(fmaxf(a1 * inv, 0.f));
    o.z = f2bu(fmaxf(a2 * inv, 0.f)); o.w = f2bu(fmaxf(a3 * inv, 0.f));
    *reinterpret_cast<ushort4*>(
        reinterpret_cast<unsigned short*>(out) + (size_t)d * KDIM + col) = o;
}

// ---------------------------------------------------------------------------
// Macro score vectors + skinny dots + softmax (node_paper never materialized)
// ---------------------------------------------------------------------------
__global__ void prep_v(const float* __restrict__ Ww, const float* __restrict__ Wc,
                       const float* __restrict__ Wn, const float* __restrict__ attn,
                       float* __restrict__ vbuf)
{
    int id = blockIdx.x * blockDim.x + threadIdx.x;
    if (id >= 3 * 2048) return;
    int which = id >> 11;
    int rem = id & 2047;
    int h = rem >> 8, k = rem & 255;
    const float* Wsrc = which == 0 ? Ww : (which == 1 ? Wc : Wn);
    int aoff = which == 2 ? 0 : 32;
    float s = 0.f;
    #pragma unroll 8
    for (int d = 0; d < 32; ++d)
        s += Wsrc[(size_t)k * KDIM + h * 32 + d] * attn[h * 64 + aoff + d];
    vbuf[which * 2048 + h * 256 + k] = fin(s);
}

template<typename T>
__global__ void macro_dot(const T* __restrict__ A, const float* __restrict__ v0,
                          float* __restrict__ out, int N)
{
    int id = blockIdx.x * blockDim.x + threadIdx.x;
    if (id >= N * NHEAD) return;
    int n = id >> 3, h = id & 7;
    const float* vh = v0 + h * 256;
    float s = 0.f;
    if constexpr (std::is_same<T, float>::value) {
        const float* row = A + (size_t)n * KDIM;
        for (int k = 0; k < KDIM; k += 4) {
            float4 a = *reinterpret_cast<const float4*>(row + k);
            float4 b = *reinterpret_cast<const float4*>(vh + k);
            s += a.x * b.x + a.y * b.y + a.z * b.z + a.w * b.w;
        }
    } else {
        const unsigned short* row =
            reinterpret_cast<const unsigned short*>(A) + (size_t)n * KDIM;
        for (int k = 0; k < KDIM; k += 4) {
            ushort4 a = *reinterpret_cast<const ushort4*>(row + k);
            float4 b = *reinterpret_cast<const float4*>(vh + k);
            s += us2f(a.x) * b.x + us2f(a.y) * b.y + us2f(a.z) * b.z + us2f(a.w) * b.w;
        }
    }
    out[id] = fin(s);
}

__global__ void score_kernel(const float* __restrict__ dotL, const float* __restrict__ dotW,
                             const float* __restrict__ dotC,
                             float* __restrict__ ow, float* __restrict__ oc, int total)
{
    int i = blockIdx.x * blockDim.x + threadIdx.x;
    if (i >= total) return;
    float sw = dotL[i] + dotW[i]; sw = sw > 0.f ? sw : SLOPE * sw;
    float sc = dotL[i] + dotC[i]; sc = sc > 0.f ? sc : SLOPE * sc;
    float m = fmaxf(sw, sc);
    float ew = expf(sw - m), ec = expf(sc - m);
    float inv = 1.f / (ew + ec);
    ow[i] = fin(ew * inv);
    oc[i] = fin(ec * inv);
}

// ---------------------------------------------------------------------------
extern "C" void kernel_launch(void* const* d_in, const int* in_sizes, int n_in,
                              void* d_out, int out_size, void* d_ws, size_t ws_size,
                              hipStream_t stream)
{
    static const int expected[24] = {
        12800000, 12800000, 65536, 65536, 512, 512, 65536, 65536,
        65536, 65536, 65536, 512, 65536, 256, 65536, 256, 1, 1,
        400000, 400000, 400000, 400000, 400000, 400000};
    float marker = 0.f;
    if (n_in != 24) marker = 500.f;
    else {
        for (int i = 0; i < 24; ++i)
            if (in_sizes[i] != expected[i]) { marker = 200.f + 8.f * i; break; }
    }
    if (marker == 0.f && out_size != 25600000) marker = 600.f + (float)(out_size / 1000000);
    if (marker == 0.f && ws_size < 51200000ull) marker = 1000.f + (float)(ws_size / 1000000ull);
    if (marker != 0.f) {
        fill_marker<<<(out_size + 255) / 256, 256, 0, stream>>>((float*)d_out, out_size, marker);
        return;
    }

    const float* feats_a  = (const float*)d_in[0];
    const float* feats_p  = (const float*)d_in[1];
    const float* W_mic_a  = (const float*)d_in[2];
    const float* W_mic_p  = (const float*)d_in[3];
    const float* attn_a   = (const float*)d_in[4];
    const float* attn_p   = (const float*)d_in[5];
    const float* W_node_p = (const float*)d_in[7];
    const float* W_rel_w  = (const float*)d_in[8];
    const float* W_rel_wb = (const float*)d_in[9];
    const float* W_rel_c  = (const float*)d_in[10];
    const float* attn_mac = (const float*)d_in[11];
    const float* W_res_a  = (const float*)d_in[12];
    const float* b_res_a  = (const float*)d_in[13];
    const float* W_res_p  = (const float*)d_in[14];
    const float* b_res_p  = (const float*)d_in[15];
    const float* rw_a     = (const float*)d_in[16];
    const float* rw_p     = (const float*)d_in[17];
    const int* w_src  = (const int*)d_in[18];
    const int* w_dst  = (const int*)d_in[19];
    const int* wb_src = (const int*)d_in[20];
    const int* wb_dst = (const int*)d_in[21];
    const int* c_src  = (const int*)d_in[22];
    const int* c_dst  = (const int*)d_in[23];

    const int NB = N_PAPER * KDIM;            // 12.8M elems
    // ---- d_out (f32, 102.4MB): [author 51.2MB][paper 51.2MB] ----
    float* Oa_f = (float*)d_out;
    float* Op_f = Oa_f + NB;
    bf16* Oa_b = (bf16*)d_out;                // P_a -> r_written_by (author lower)
    bf16* Op_b = (bf16*)Op_f;                 // P_p -> rf_writes    (paper lower)
    char* au_up = (char*)d_out + 25600000;    // author upper 25.6MB
    bf16*  Cslot = (bf16*)au_up;              // r_cites
    bf16*  BTa0  = (bf16*)au_up;              // later: W_res_p BT (Cslot dead)
    bf16*  BTa1  = BTa0 + 65536;              //        W_rel_wb BT
    char* pu = (char*)d_out + 76800000;       // paper upper 25.6MB
    float* dotW = (float*)pu;
    float* dotC = dotW + 400000;
    float* dotL = dotW + 800000;
    float* sc_w = dotW + 1200000;
    float* sc_c = dotW + 1600000;
    float* vbuf = dotW + 2000000;             // 6144 f32
    bf16* BT0 = (bf16*)(pu + 10000000);       // early BT slots (128KB each)
    bf16* BT1 = BT0 + 65536;
    bf16* BT2 = BT1 + 65536;
    bf16* BT3 = BT2 + 65536;
    // ---- d_ws (51.2e6 B): [A_ws 25.6MB][X 25.6MB] ----
    bf16* A_ws = (bf16*)d_ws;                 // r_writes -> fused_paper
    bf16* BTw  = (bf16*)d_ws;                 // W_res_a BT (after fused dead)
    char* Xb   = (char*)d_ws + 25600000;
    float* el_w  = (float*)Xb;                // 5 x 400,000 f32 (8MB)
    float* er_w  = el_w + 400000;
    float* el_p  = el_w + 800000;
    float* er_wb = el_w + 1200000;
    float* er_c  = el_w + 1600000;
    int*  csr    = (int*)(el_w + 2000000);    // 3 x 500004 ints (~6MB)
    bf16* Xslot  = (bf16*)Xb;                 // later: rf_written_by (25.6MB)

    dim3 mg(2, (N_PAPER + 127) / 128);
    int hdB = (N_PAPER * NHEAD + 255) / 256;
    int eB  = (NEDGE + 255) / 256;
    int gB  = (N_PAPER + 3) / 4;

    // ---- 1: micro projections (MFMA) ----
    prep_bt<<<256, 256, 0, stream>>>(W_mic_a, BT0);
    prep_bt<<<256, 256, 0, stream>>>(W_mic_p, BT1);
    mfma_gemm<0, float><<<mg, 256, 0, stream>>>(feats_a, BT0, N_AUTHOR, Oa_b,
        nullptr, nullptr, nullptr, nullptr, nullptr, nullptr);
    mfma_gemm<0, float><<<mg, 256, 0, stream>>>(feats_p, BT1, N_PAPER, Op_b,
        nullptr, nullptr, nullptr, nullptr, nullptr, nullptr);

    // ---- 2: micro attention dots ----
    head_dot<<<hdB, 256, 0, stream>>>(Oa_b, attn_a, 0,  N_AUTHOR, el_w);
    head_dot<<<hdB, 256, 0, stream>>>(Op_b, attn_a, 32, N_PAPER,  er_w);
    head_dot<<<hdB, 256, 0, stream>>>(Op_b, attn_p, 0,  N_PAPER,  el_p);
    head_dot<<<hdB, 256, 0, stream>>>(Oa_b, attn_p, 32, N_AUTHOR, er_wb);
    head_dot<<<hdB, 256, 0, stream>>>(Op_b, attn_p, 32, N_PAPER,  er_c);

    // ---- 3: relations via CSR gather (no atom-scatter).
    // r0 writes: feat P_a(Oa_b) -> A_ws
    // r1 written_by: feat P_p(Op_b) -> Oa_b (P_a dead after r0)
    // r2 cites: feat P_p(Op_b) -> Cslot (distinct buffer; gather forbids in-place)
    const int* rsrc[3]     = {w_src, wb_src, c_src};
    const int* rdst[3]     = {w_dst, wb_dst, c_dst};
    const float* rel_el[3] = {el_w, el_p, el_p};
    const float* rel_er[3] = {er_w, er_wb, er_c};
    const bf16* rfeat[3]   = {Oa_b, Op_b, Op_b};
    bf16* rout[3]          = {A_ws, Oa_b, Cslot};
    for (int r = 0; r < 3; ++r) {
        int* off  = csr + r * 500004;
        int* woff = off + 50001;
        int* gsrc = woff + 50000;
        hipMemsetAsync(woff, 0, 50000 * sizeof(int), stream);
        edge_hist<<<eB, 256, 0, stream>>>(rdst[r], woff, NEDGE);
        scan_off<<<1, 1024, 0, stream>>>(woff, off, woff, N_PAPER);
        edge_scatter<<<eB, 256, 0, stream>>>(rsrc[r], rdst[r], woff, gsrc, NEDGE);
        gat_gather<<<gB, 256, 0, stream>>>(off, gsrc, rel_el[r], rel_er[r],
                                           rfeat[r], rout[r], N_PAPER);
    }
    // A_ws=r_writes, Oa_b=r_written_by, Cslot=r_cites; P_p (Op_b) dead.

    // ---- 4: macro scores via vector algebra ----
    prep_v<<<24, 256, 0, stream>>>(W_rel_w, W_rel_c, W_node_p, attn_mac, vbuf);
    macro_dot<bf16><<<hdB, 256, 0, stream>>>(A_ws,  vbuf,        dotW, N_PAPER);
    macro_dot<bf16><<<hdB, 256, 0, stream>>>(Cslot, vbuf + 2048, dotC, N_PAPER);
    macro_dot<float><<<hdB, 256, 0, stream>>>(feats_p, vbuf + 4096, dotL, N_PAPER);
    score_kernel<<<hdB, 256, 0, stream>>>(dotL, dotW, dotC, sc_w, sc_c, N_PAPER * NHEAD);

    // ---- 5: rf_writes = r_writes(A_ws) @ W_rel_w -> Op_b (P_p dead) ----
    prep_bt<<<256, 256, 0, stream>>>(W_rel_w, BT2);
    mfma_gemm<0, bf16><<<mg, 256, 0, stream>>>(A_ws, BT2, N_PAPER, Op_b,
        nullptr, nullptr, nullptr, nullptr, nullptr, nullptr);
    // ---- 6: fused = sc_w*rf_writes(Op_b) + sc_c*(r_cites(Cslot) @ W_rel_c) -> A_ws ----
    prep_bt<<<256, 256, 0, stream>>>(W_rel_c, BT3);
    mfma_gemm<1, bf16><<<mg, 256, 0, stream>>>(Cslot, BT3, N_PAPER, A_ws,
        nullptr, nullptr, nullptr, Op_b, sc_w, sc_c);
    // ---- 7: paper gated residual -> Op_f FINAL (BT in au_up; Cslot dead) ----
    prep_bt<<<256, 256, 0, stream>>>(W_res_p, BTa0);
    mfma_gemm<2, float><<<mg, 256, 0, stream>>>(feats_p, BTa0, N_PAPER, Op_f,
        b_res_p, A_ws, rw_p, nullptr, nullptr, nullptr);
    // ---- 8: rf_written_by = r_written_by(Oa_b) @ W_rel_wb -> Xslot (CSR dead) ----
    prep_bt<<<256, 256, 0, stream>>>(W_rel_wb, BTa1);
    mfma_gemm<0, bf16><<<mg, 256, 0, stream>>>(Oa_b, BTa1, N_AUTHOR, Xslot,
        nullptr, nullptr, nullptr, nullptr, nullptr, nullptr);
    // ---- 9: author gated residual -> Oa_f FINAL (BT in A_ws; fused dead) ----
    prep_bt<<<256, 256, 0, stream>>>(W_res_a, BTw);
    mfma_gemm<2, float><<<mg, 256, 0, stream>>>(feats_a, BTw, N_AUTHOR, Oa_f,
        b_res_a, Xslot, rw_a, nullptr, nullptr, nullptr);
}